// Round 3
// baseline (486.512 us; speedup 1.0000x reference)
//
#include <hip/hip_runtime.h>

// GCN scatter-aggregate, round 9: atomic-scatter CSR build (no sort).
//   memset  : deg + csum zero
//   k_pre   : Wf fragment conversion || zero dummy h2 row
//   k_deg   : deg[d]++ atomics + per-chunk (1024 nodes) edge counts
//   k_scan2 : 1-block exclusive scan of 98 chunk counts -> coffs; rowptr[N]=E
//   k_scan3 : per-chunk local scan of deg -> rowptr, cur
//   k_gemm  : h = bf16(rsqrt(deg) * (x @ W))  (MFMA, fp32 accumulate)
//   k_scatter: srcs[atomicAdd(&cur[dst],1)] = src   (grouping, order-free)
//   k_aggr  : out[n] = rsqrt(deg[n]) * sum(h[srcs]) + bias
// Inputs: x fp32 [N,256], edge_index int32 [2,E] (row=dst, col=src),
//         W fp32 [256,128], bias fp32 [128]. Output fp32 [N,128].

#define N_FEAT 256
#define N_HID  128
#define NCHMAX 128        // >= ceil(100000/1024) = 98 chunk counters
#define CHUNK_LOG 10      // 1024 nodes per scan chunk

typedef float fx4    __attribute__((ext_vector_type(4)));
typedef float f32x16 __attribute__((ext_vector_type(16)));
typedef short bf16x8 __attribute__((ext_vector_type(8)));
typedef unsigned int u32x4 __attribute__((ext_vector_type(4)));

__device__ __forceinline__ float bf2f(unsigned int u) {
    return __uint_as_float(u << 16);
}
__device__ __forceinline__ float bf2f_hi(unsigned int u) {
    return __uint_as_float(u & 0xFFFF0000u);
}
__device__ __forceinline__ unsigned int f2bf(float f) {
    unsigned int u = __float_as_uint(f);
    return (u + 0x7FFFu + ((u >> 16) & 1u)) >> 16;  // round-nearest-even
}
__device__ __forceinline__ float deg2dis(int dg) {
    return (dg > 0) ? rsqrtf((float)dg) : 0.0f;
}

// ---- k_pre: Wf fragment conversion + dummy-row zero -------------------------
// Blocks 0..15: W -> fragment-ready bf16 (B-operand of mfma_f32_32x32x16_bf16).
// Frag f = kstep*4 + ntile; lane supplies B[k=kstep*16+(lane>>5)*8+j][n=ntile*32+(lane&31)].
// Block 16: zero dummy h2 row (tail clamp target of k_aggr).
__global__ __launch_bounds__(256) void k_pre(const float* __restrict__ W,
                                             uint4* __restrict__ Wf,
                                             unsigned int* __restrict__ h2d) {
    const int b = blockIdx.x, t = threadIdx.x;
    if (b < 16) {
        int i = b * 256 + t;                  // 0..4095
        int lane = i & 63, f = i >> 6;
        int kstep = f >> 2, nt = f & 3;
        int n  = nt * 32 + (lane & 31);
        int kb = kstep * 16 + (lane >> 5) * 8;
        unsigned s[8];
#pragma unroll
        for (int j = 0; j < 8; ++j) s[j] = f2bf(W[(kb + j) * N_HID + n]);
        uint4 o;
        o.x = s[0] | (s[1] << 16);
        o.y = s[2] | (s[3] << 16);
        o.z = s[4] | (s[5] << 16);
        o.w = s[6] | (s[7] << 16);
        Wf[i] = o;
    } else {
        if (t < 64) h2d[t] = 0;               // dummy zero row h2[N]
    }
}

// ---- k_deg: degree atomics + per-chunk edge counts --------------------------
// 782 blocks x 2 passes x 256 threads x int4 = covers E=1.6M dst ids.
__global__ __launch_bounds__(256) void k_deg(const int* __restrict__ ei,
                                             int* __restrict__ deg,
                                             int* __restrict__ csum, int E) {
    __shared__ int hist[NCHMAX];
    const int t = threadIdx.x;
    for (int i = t; i < NCHMAX; i += 256) hist[i] = 0;
    __syncthreads();
#pragma unroll
    for (int p = 0; p < 2; ++p) {
        int idx = blockIdx.x * 2048 + p * 1024 + t * 4;
        if (idx < E) {
            int4 d4 = *(const int4*)(ei + idx);
            atomicAdd(&deg[d4.x], 1);
            atomicAdd(&deg[d4.y], 1);
            atomicAdd(&deg[d4.z], 1);
            atomicAdd(&deg[d4.w], 1);
            atomicAdd(&hist[d4.x >> CHUNK_LOG], 1);
            atomicAdd(&hist[d4.y >> CHUNK_LOG], 1);
            atomicAdd(&hist[d4.z >> CHUNK_LOG], 1);
            atomicAdd(&hist[d4.w >> CHUNK_LOG], 1);
        }
    }
    __syncthreads();
    for (int i = t; i < NCHMAX; i += 256) {
        int h = hist[i];
        if (h) atomicAdd(&csum[i], h);
    }
}

// ---- k_scan2: 1-block exclusive scan of chunk counts ------------------------
__global__ __launch_bounds__(128) void k_scan2(const int* __restrict__ csum,
                                               int* __restrict__ coffs,
                                               int* __restrict__ rowptr,
                                               int nch, int N, int E) {
    __shared__ int sc[128];
    const int t = threadIdx.x;
    int v = (t < nch) ? csum[t] : 0;
    sc[t] = v;
    __syncthreads();
    for (int off = 1; off < 128; off <<= 1) {
        int a = sc[t];
        int b = (t >= off) ? sc[t - off] : 0;
        __syncthreads();
        sc[t] = a + b;
        __syncthreads();
    }
    coffs[t] = sc[t] - v;   // exclusive
    if (t == 0) rowptr[N] = E;
}

// ---- k_scan3: per-chunk local scan -> rowptr, cur ---------------------------
// Chunk = 1024 nodes, 256 threads x int4. N % 4 == 0 so int4 never straddles N.
__global__ __launch_bounds__(256) void k_scan3(const int* __restrict__ deg,
                                               const int* __restrict__ coffs,
                                               int* __restrict__ rowptr,
                                               int* __restrict__ cur, int N) {
    __shared__ int sc[256];
    const int b = blockIdx.x, t = threadIdx.x;
    const int i0 = (b << CHUNK_LOG) + t * 4;
    int4 d4 = make_int4(0, 0, 0, 0);
    if (i0 < N) d4 = *(const int4*)(deg + i0);
    int s = d4.x + d4.y + d4.z + d4.w;
    sc[t] = s;
    __syncthreads();
    for (int off = 1; off < 256; off <<= 1) {
        int a = sc[t];
        int c = (t >= off) ? sc[t - off] : 0;
        __syncthreads();
        sc[t] = a + c;
        __syncthreads();
    }
    int base = coffs[b] + sc[t] - s;
    if (i0 < N) {
        int4 r;
        r.x = base;
        r.y = r.x + d4.x;
        r.z = r.y + d4.y;
        r.w = r.z + d4.z;
        *(int4*)(rowptr + i0) = r;
        *(int4*)(cur + i0) = r;
    }
}

// ---- k_scatter: group edges by dst (order within segment is arbitrary) ------
__global__ __launch_bounds__(256) void k_scatter(const int* __restrict__ ei,
                                                 int* __restrict__ cur,
                                                 int* __restrict__ srcs, int E) {
    const int t = threadIdx.x;
#pragma unroll
    for (int p = 0; p < 2; ++p) {
        int idx = blockIdx.x * 2048 + p * 1024 + t * 4;
        if (idx < E) {
            int4 d4 = *(const int4*)(ei + idx);
            int4 s4 = *(const int4*)(ei + E + idx);
            int p0 = atomicAdd(&cur[d4.x], 1);
            int p1 = atomicAdd(&cur[d4.y], 1);
            int p2 = atomicAdd(&cur[d4.z], 1);
            int p3 = atomicAdd(&cur[d4.w], 1);
            srcs[p0] = s4.x;
            srcs[p1] = s4.y;
            srcs[p2] = s4.z;
            srcs[p3] = s4.w;
        }
    }
}

// ---- h = bf16(dis * (x @ W)) via MFMA, no LDS -------------------------------
// Block = 4 waves; wave w covers rows mbase+w*32 .. +31, all 128 cols.
__global__ __launch_bounds__(256) void k_gemm(const float* __restrict__ x,
                                              const uint4* __restrict__ Wf,
                                              const int* __restrict__ deg,
                                              unsigned short* __restrict__ h2s,
                                              int N) {
    const int wave = threadIdx.x >> 6;
    const int lane = threadIdx.x & 63;
    const int half = lane >> 5;          // k sub-block 0/1 (8 elems each)
    const int lm   = lane & 31;
    const int mbase = blockIdx.x * 128 + wave * 32;
    const int arow  = min(mbase + lm, N - 1);   // clamp; garbage rows discarded

    const fx4* xr = (const fx4*)(x + (size_t)arow * N_FEAT) + half * 2;

    f32x16 acc0 = {0}, acc1 = {0}, acc2 = {0}, acc3 = {0};

#pragma unroll
    for (int ks = 0; ks < 16; ++ks) {
        fx4 a0 = xr[ks * 4];          // k = ks*16 + half*8 + (0..3)
        fx4 a1 = xr[ks * 4 + 1];      //                  + (4..7)
        union { bf16x8 v; unsigned u[4]; } A;
        A.u[0] = f2bf(a0.x) | (f2bf(a0.y) << 16);
        A.u[1] = f2bf(a0.z) | (f2bf(a0.w) << 16);
        A.u[2] = f2bf(a1.x) | (f2bf(a1.y) << 16);
        A.u[3] = f2bf(a1.z) | (f2bf(a1.w) << 16);
        union { bf16x8 v; uint4 q; } B0, B1, B2, B3;
        B0.q = Wf[(ks * 4 + 0) * 64 + lane];
        B1.q = Wf[(ks * 4 + 1) * 64 + lane];
        B2.q = Wf[(ks * 4 + 2) * 64 + lane];
        B3.q = Wf[(ks * 4 + 3) * 64 + lane];
        acc0 = __builtin_amdgcn_mfma_f32_32x32x16_bf16(A.v, B0.v, acc0, 0, 0, 0);
        acc1 = __builtin_amdgcn_mfma_f32_32x32x16_bf16(A.v, B1.v, acc1, 0, 0, 0);
        acc2 = __builtin_amdgcn_mfma_f32_32x32x16_bf16(A.v, B2.v, acc2, 0, 0, 0);
        acc3 = __builtin_amdgcn_mfma_f32_32x32x16_bf16(A.v, B3.v, acc3, 0, 0, 0);
    }

    // C/D: col = lane&31, row = (r&3) + 8*(r>>2) + 4*(lane>>5)   [m74/m101]
#pragma unroll
    for (int r = 0; r < 16; ++r) {
        int row  = (r & 3) + 8 * (r >> 2) + 4 * half;
        int node = mbase + row;
        if (node < N) {
            float dn = deg2dis(deg[node]);
            size_t o = (size_t)node * N_HID + lm;
            h2s[o +  0] = (unsigned short)f2bf(dn * acc0[r]);
            h2s[o + 32] = (unsigned short)f2bf(dn * acc1[r]);
            h2s[o + 64] = (unsigned short)f2bf(dn * acc2[r]);
            h2s[o + 96] = (unsigned short)f2bf(dn * acc3[r]);
        }
    }
}

// ---- aggregation: out[n] = dis[n] * sum(h[srcs]) + bias ---------------------
// One wave per node. 16-edge chunks: one coalesced srcs read, ds_bpermute
// distribution, 4x dwordx4 gathers (each covers 4 edge rows = 1 KB).
// Lane-group j = lane>>4 handles edge 4g+j of the chunk; lane q = lane&15
// holds hidden dims 8q..8q+7. Tail edges clamp to zeroed dummy row h2[N].
__global__ __launch_bounds__(256) void k_aggr(const int* __restrict__ rowptr,
                                              const int* __restrict__ srcs,
                                              const u32x4* __restrict__ h2q,
                                              const int* __restrict__ deg,
                                              const float* __restrict__ bias,
                                              float4* __restrict__ out4, int N) {
    const int n    = blockIdx.x * 4 + (threadIdx.x >> 6);
    const int lane = threadIdx.x & 63;
    if (n >= N) return;
    const int j = lane >> 4;      // edge sub-slot within each gather
    const int q = lane & 15;      // 16B chunk (dims 8q..8q+7) within a row

    int i   = rowptr[n];
    int end = rowptr[n + 1];
    float dn = deg2dis(deg[n]);   // hoisted: overlaps with srcs/gather latency

    float a[8];
#pragma unroll
    for (int k = 0; k < 8; ++k) a[k] = 0.0f;

    for (; i < end; i += 16) {
        // one coalesced 64B read covers 16 src ids (srcs padded by 16 ints)
        int cl = srcs[i + q];
#pragma unroll
        for (int g = 0; g < 4; ++g) {
            int cg  = __shfl(cl, 4 * g + j, 64);   // ds_bpermute
            int idx = i + 4 * g + j;
            cg = (idx < end) ? cg : N;             // dummy zero row for tail
            u32x4 v = h2q[(size_t)cg * 16 + q];    // dwordx4: 4 rows / instr
            a[0] += bf2f(v[0]);  a[1] += bf2f_hi(v[0]);
            a[2] += bf2f(v[1]);  a[3] += bf2f_hi(v[1]);
            a[4] += bf2f(v[2]);  a[5] += bf2f_hi(v[2]);
            a[6] += bf2f(v[3]);  a[7] += bf2f_hi(v[3]);
        }
    }

    // sum the 4 lane-groups (once per node)
#pragma unroll
    for (int k = 0; k < 8; ++k) {
        a[k] += __shfl_xor(a[k], 16, 64);
        a[k] += __shfl_xor(a[k], 32, 64);
    }

    if (lane < 16) {
        const float4* b4 = (const float4*)bias;
        float4 b0 = b4[q * 2], b1 = b4[q * 2 + 1];
        float4 o0, o1;
        o0.x = dn * a[0] + b0.x;  o0.y = dn * a[1] + b0.y;
        o0.z = dn * a[2] + b0.z;  o0.w = dn * a[3] + b0.w;
        o1.x = dn * a[4] + b1.x;  o1.y = dn * a[5] + b1.y;
        o1.z = dn * a[6] + b1.z;  o1.w = dn * a[7] + b1.w;
        out4[(size_t)n * 32 + q * 2]     = o0;
        out4[(size_t)n * 32 + q * 2 + 1] = o1;
    }
}

extern "C" void kernel_launch(void* const* d_in, const int* in_sizes, int n_in,
                              void* d_out, int out_size, void* d_ws, size_t ws_size,
                              hipStream_t stream) {
    const float* x    = (const float*)d_in[0];   // fp32 [N,256]
    const int*   ei   = (const int*)d_in[1];     // int32 [2,E]
    const float* W    = (const float*)d_in[2];   // fp32 [256,128]
    const float* bias = (const float*)d_in[3];   // fp32 [128]

    const int N = in_sizes[0] / N_FEAT;   // 100000
    const int E = in_sizes[1] / 2;        // 1600000
    const int nch = (N + 1023) >> CHUNK_LOG;   // 98 scan chunks

    // workspace layout (~33 MB)
    char* ws = (char*)d_ws;
    size_t off = 0;
    int*          deg    = (int*)(ws + off);   off += (size_t)N * 4;
    int*          csum   = (int*)(ws + off);   off += NCHMAX * 4;   // contiguous w/ deg
    int*          coffs  = (int*)(ws + off);   off += NCHMAX * 4;
    int*          rowptr = (int*)(ws + off);   off += (size_t)(N + 1) * 4 + 12;
    int*          cur    = (int*)(ws + off);   off += (size_t)N * 4;
    int*          srcs   = (int*)(ws + off);   off += (size_t)E * 4 + 64;  // +16 pad
    uint4*        Wf     = (uint4*)(ws + off); off += 4096 * 16;   // 64 KB
    unsigned int* h2     = (unsigned int*)(ws + off);  // (N+1)*64 dwords

    const int eb = (E + 2047) / 2048;     // 782 edge blocks

    (void)hipMemsetAsync(deg, 0, ((size_t)N + NCHMAX) * 4, stream);  // deg + csum

    k_pre<<<17, 256, 0, stream>>>(W, (uint4*)Wf, h2 + (size_t)N * 64);
    k_deg<<<eb, 256, 0, stream>>>(ei, deg, csum, E);
    k_scan2<<<1, 128, 0, stream>>>(csum, coffs, rowptr, nch, N, E);
    k_scan3<<<nch, 256, 0, stream>>>(deg, coffs, rowptr, cur, N);
    k_gemm<<<(N + 127) / 128, 256, 0, stream>>>(x, Wf, deg,
                                                (unsigned short*)h2, N);
    k_scatter<<<eb, 256, 0, stream>>>(ei, cur, srcs, E);
    k_aggr<<<(N + 3) / 4, 256, 0, stream>>>(rowptr, srcs, (const u32x4*)h2,
                                            deg, bias, (float4*)d_out, N);
}